// Round 28
// baseline (88.740 us; speedup 1.0000x reference)
//
#include <hip/hip_runtime.h>
#include <stdint.h>

static constexpr int   Bn      = 32;
static constexpr int   Tn      = 2000;
static constexpr int   Hn      = 512;
static constexpr int   Ln      = 256;     // max_label_len
static constexpr float kThresh = 0.95f;
static constexpr int   TCHUNK  = 40;      // meta granularity (consumer chunk)
static constexpr int   NTCH    = Tn / TCHUNK;   // 50
static constexpr int   CSPLIT  = 2;       // consumer blocks per (tc, b)
static constexpr int   MSTRIDE = 64;            // meta entries per row (padded)
static constexpr unsigned PUBF = 0x40000000u;   // published flag (low word)

// ---------------------------------------------------------------------------
// Fused producer-consumer CIF. R28 = R23 (proven equilibrium: LDS 8704,
// VGPR 44, 3232 co-resident blocks, 56.1 us) minus the consumer's wasted
// work. R24/R26/R27 (blocks, occupancy, ILP depth) were all flat -> the
// remaining cost is STRUCTURAL: (a) rows after a chunk's last fire were
// read twice (once into the discarded open-tail acc, once by the next
// chunk's straddler) ~20% of hidden traffic; (b) every consumer ran a
// serial multi-chunk walk-back before its first h-load; (c) no-fire chunks
// read 40 h-rows for nothing.
// Fix: producer publishes a SECOND 8-B meta per chunk: (rem_last,
// PUB|lastT+1) -- the global last-fire position/remainder at chunk start
// (tracked with 2 off-critical-path selects per step). Consumers pre-scan
// their 40 alphas (scalar, L2-hot) for jlast/nf, then:
//   no fire -> return with ZERO h-loads;
//   else    -> h-loop from meta2's t_prev to jlast ONLY (open tail skipped
//              -- it's the next consumer's property; walk-back gone).
// Stored values and their ascending-t accumulation order are IDENTICAL
// (absmax 0.0 preserved); only dead/duplicate loads are removed.
// ---------------------------------------------------------------------------
__global__ __launch_bounds__(64, 1) void cif_fused_kernel(
    const float* __restrict__ hidden,
    const float* __restrict__ alphas,
    uint64_t* __restrict__ meta,      // [Bn*MSTRIDE] (I, PUB|fc)
    uint64_t* __restrict__ meta2,     // [Bn*MSTRIDE] (rem_last, PUB|lastT+1)
    float* __restrict__ out) {
  const int lane = threadIdx.x;
  __shared__ __align__(16) float alds[Tn + 64];   // +pad: tail prefetch safe

  if (blockIdx.x < Bn) {
    // ---------------- producer: serial scan for row b ----------------
    __builtin_amdgcn_s_setprio(3);
    const int b = blockIdx.x;
    {  // stage row -> LDS, coalesced (one-time cost, outside the chain)
      const float4* __restrict__ arow =
          reinterpret_cast<const float4*>(alphas + (size_t)b * Tn);
      for (int i = lane; i < Tn / 4; i += 64)
        *reinterpret_cast<float4*>(&alds[4 * i]) = arow[i];
      for (int i = Tn / 4 + lane; i < (Tn + 64) / 4; i += 64)
        *reinterpret_cast<float4*>(&alds[4 * i]) =
            make_float4(0.f, 0.f, 0.f, 0.f);
    }
    __syncthreads();

    const float4* __restrict__ lds4 =
        reinterpret_cast<const float4*>(&alds[0]);
    float I       = 0.0f;
    int   fc      = 0;
    int   lastT1  = 0;       // lastT+1 (0 = none yet)
    float lastRem = 0.0f;

    float4 q0 = lds4[0], q1 = lds4[1], q2 = lds4[2], q3 = lds4[3],
           q4 = lds4[4];
    int rd = 5;

    auto step4 = [&](const float4& q, int tbase) {
#pragma unroll
      for (int j = 0; j < 4; ++j) {
        const float a = (j == 0) ? q.x : (j == 1) ? q.y : (j == 2) ? q.z : q.w;
        const float integ = I + a;            // reference op order
        const bool  fire  = integ > kThresh;
        const float cw    = 1.0f - I;         // dist_completion
        lastT1  = fire ? (tbase + j + 1) : lastT1;   // off critical path
        lastRem = fire ? (a - cw) : lastRem;         // off critical path
        I  = fire ? (integ - 1.0f) : integ;
        fc += fire ? 1 : 0;
      }
    };

    for (int c = 0; c < 100; ++c) {           // 20 steps per iteration
      if (lane == 0 && (c & 1) == 0) {        // state at t = 20c -> chunk c/2
        const uint64_t v1 = ((uint64_t)__float_as_uint(I) << 32) |
                            (uint64_t)(PUBF | (unsigned)fc);
        __hip_atomic_store(&meta[(size_t)b * MSTRIDE + (c >> 1)], v1,
                           __ATOMIC_RELAXED, __HIP_MEMORY_SCOPE_AGENT);
        const uint64_t v2 = ((uint64_t)__float_as_uint(lastRem) << 32) |
                            (uint64_t)(PUBF | (unsigned)lastT1);
        __hip_atomic_store(&meta2[(size_t)b * MSTRIDE + (c >> 1)], v2,
                           __ATOMIC_RELAXED, __HIP_MEMORY_SCOPE_AGENT);
      }
      const int t0 = c * 20;
      step4(q0, t0);      q0 = lds4[rd + 0];  // reload right after consume
      step4(q1, t0 + 4);  q1 = lds4[rd + 1];
      step4(q2, t0 + 8);  q2 = lds4[rd + 2];
      step4(q3, t0 + 12); q3 = lds4[rd + 3];
      step4(q4, t0 + 16); q4 = lds4[rd + 4];
      rd += 5;
    }
    return;
  }

  // ---------------- consumer: (chunk tc, row b, half) ----------------
  const int idx  = blockIdx.x - Bn;
  const int b    = idx & (Bn - 1);
  const int q    = idx >> 5;                // 0..NTCH*CSPLIT-1, low q first
  const int tc   = q >> 1;                  // low blockIdx -> low tc
  const int half = q & 1;
  const int t_start = tc * TCHUNK;
  const int col  = half * (Hn / CSPLIT) + lane * 4;   // float4 per lane

  auto wait64 = [&](uint64_t* arr, int c) -> uint64_t {
    const uint64_t* p = &arr[(size_t)b * MSTRIDE + c];
    uint64_t v;
    for (;;) {
      v = __hip_atomic_load(p, __ATOMIC_RELAXED, __HIP_MEMORY_SCOPE_AGENT);
      if ((unsigned)v & PUBF) break;
      __builtin_amdgcn_s_sleep(16);
    }
    return v;
  };

  const float* __restrict__ arow = alphas + (size_t)b * Tn;

  // Chunk-start state (bit-exact from producer).
  float I; int s;
  if (tc == 0) { I = 0.0f; s = 0; }
  else {
    const uint64_t v = wait64(meta, tc);
    I = __uint_as_float((unsigned)(v >> 32));
    s = (int)((unsigned)v & 0xFFFFu);
  }

  float* __restrict__ const obase = out + (size_t)b * Ln * Hn + col;

  // Pre-scan own alphas (scalar, L2-hot): last fire index + fire count.
  int jlast = -1, nf = 0;
  {
    float Ip = I;
#pragma unroll
    for (int j = 0; j < TCHUNK; ++j) {
      const float a     = arow[t_start + j];
      const float integ = Ip + a;             // reference op order
      const bool  fire  = integ > kThresh;
      jlast = fire ? j : jlast;
      nf   += fire ? 1 : 0;
      Ip = fire ? (integ - 1.0f) : integ;
    }
  }

  if (jlast < 0) {                 // no fire in this chunk: zero h-loads
    if (tc == NTCH - 1) {
      const float4 z = make_float4(0.f, 0.f, 0.f, 0.f);
      for (int s2 = (s < Ln ? s : Ln); s2 < Ln; ++s2)
        *reinterpret_cast<float4*>(obase + (size_t)s2 * Hn) = z;
    }
    return;
  }

  // Straddler opening directly from meta2 (no walk-back).
  int   t_prev; float rem_prev;
  if (tc == 0) { t_prev = -1; rem_prev = 0.0f; }
  else {
    const uint64_t v2 = wait64(meta2, tc);
    t_prev   = (int)((unsigned)v2 & 0x7FFu) - 1;
    rem_prev = __uint_as_float((unsigned)(v2 >> 32));
  }

  const float* __restrict__ hb = hidden + (size_t)b * Tn * Hn + col;
  auto loadh = [&](int t) -> float4 {
    return *reinterpret_cast<const float4*>(hb + (size_t)t * Hn);
  };

  float4 acc = make_float4(0.f, 0.f, 0.f, 0.f);
  if (t_prev >= 0) {            // opening: frame = rem * h[t_prev]
    const float4 h = loadh(t_prev);
    acc.x = rem_prev * h.x; acc.y = rem_prev * h.y;
    acc.z = rem_prev * h.z; acc.w = rem_prev * h.w;
  }
  for (int t = t_prev + 1; t < t_start; ++t) {   // straddler interior rows
    const float a  = arow[t];
    const float4 h = loadh(t);
    acc.x += a * h.x; acc.y += a * h.y;
    acc.z += a * h.z; acc.w += a * h.w;
  }

  // Replay to jlast ONLY (open tail after jlast is the next consumer's).
  float4 hc = loadh(t_start);
  for (int j = 0; j <= jlast; ++j) {
    const int t  = t_start + j;
    const int jn = (j + 1 <= jlast) ? j + 1 : jlast;
    const float4 hn = loadh(t_start + jn);   // issue BEFORE consuming hc
    const float a     = arow[t];             // uniform scalar load
    const float integ = I + a;               // reference op order
    const bool  fire  = integ > kThresh;     // wave-uniform
    if (fire) {
      const float cw = 1.0f - I;             // dist_completion
      acc.x += cw * hc.x; acc.y += cw * hc.y;
      acc.z += cw * hc.z; acc.w += cw * hc.w;
      if (s < Ln)
        *reinterpret_cast<float4*>(obase + (size_t)s * Hn) = acc;
      const float rem = a - cw;              // remainds -> opens next segment
      acc.x = rem * hc.x; acc.y = rem * hc.y;
      acc.z = rem * hc.z; acc.w = rem * hc.w;
      s += 1;
      I  = integ - 1.0f;
    } else {
      acc.x += a * hc.x; acc.y += a * hc.y;
      acc.z += a * hc.z; acc.w += a * hc.w;
      I = integ;
    }
    hc = hn;
  }
  if (tc == NTCH - 1) {                      // zero-fill never-fired slots
    const float4 z = make_float4(0.f, 0.f, 0.f, 0.f);
    for (int s2 = (s < Ln ? s : Ln); s2 < Ln; ++s2)
      *reinterpret_cast<float4*>(obase + (size_t)s2 * Hn) = z;
  }
}

extern "C" void kernel_launch(void* const* d_in, const int* in_sizes, int n_in,
                              void* d_out, int out_size, void* d_ws, size_t ws_size,
                              hipStream_t stream) {
  const float* hidden = (const float*)d_in[0];
  const float* alphas = (const float*)d_in[1];
  float* out = (float*)d_out;

  // ws layout: meta[Bn*MSTRIDE] u64 | meta2[Bn*MSTRIDE] u64 (32 KB total,
  // memset each call so stale PUB flags never leak across replays).
  uint64_t* meta  = (uint64_t*)d_ws;
  uint64_t* meta2 = meta + (size_t)Bn * MSTRIDE;
  hipMemsetAsync(meta, 0, (size_t)Bn * MSTRIDE * 2 * sizeof(uint64_t), stream);

  const int nblocks = Bn + NTCH * Bn * CSPLIT;  // 32 producers + 3200 consumers
  cif_fused_kernel<<<nblocks, 64, 0, stream>>>(hidden, alphas, meta, meta2,
                                               out);
}

// Round 29
// 56.748 us; speedup vs baseline: 1.5638x; 1.5638x over previous
//
#include <hip/hip_runtime.h>
#include <stdint.h>

static constexpr int   Bn      = 32;
static constexpr int   Tn      = 2000;
static constexpr int   Hn      = 512;
static constexpr int   Ln      = 256;     // max_label_len
static constexpr float kThresh = 0.95f;
static constexpr int   TCHUNK  = 40;      // meta granularity (consumer chunk)
static constexpr int   NTCH    = Tn / TCHUNK;   // 50
static constexpr int   CSPLIT  = 2;       // consumer blocks per (tc, b)
static constexpr int   MSTRIDE = 64;            // meta entries per row (padded)
static constexpr unsigned PUBF = 0x40000000u;   // published flag (low word)

// ---------------------------------------------------------------------------
// Fused producer-consumer CIF — R23 restored verbatim (session best:
// 56.1 us, absmax 0.0). The stable allocator equilibrium: LDS 8704 ->
// VGPR 44 (producer's depth-5 LDS rotation unspilled), 3232 blocks all
// co-resident, consumers with CSPLIT=2 + depth-2 prefetch.
// R24-R28 proved every neighboring design point is worse or null:
//   R24 CSPLIT=4: blocks beyond the 18/CU LDS residency cap just queue.
//   R25 cache warming: 3x HBM traffic (L2/L3 can't hold it), -20%.
//   R26 LDS shrink: allocator strips VGPR to 16, producer spills, -4%.
//   R27 depth-6 ILP: null -- the branchy replay issues 1 load/iter.
//   R28 meta2+prescan: serial alpha scan on post-meta critical path, -58%.
//
// Producer (blocks 0..31): LDS-staged alpha row, serial chain via depth-5
// rotation of named float4 (ds_read-fed, no vmem/arrays in the chain, ~12
// cyc/step), meta published every 40 steps as ONE relaxed 8-B atomic
// (packed (integrate, PUB|fc) -- the meta IS the flag, no fence needed).
// Consumers (one per (chunk tc, row b, half)): spin with s_sleep on
// meta[tc], bit-exact replay of chunk tc from the packed state, exclusive
// ownership of segments CLOSING in the chunk (walk-back re-derives the
// straddler opening), ascending-t accumulation = reference op order ->
// absmax 0.0; tc=NTCH-1 zero-fills [fc,256). No atomics, no pre-zero pass.
// ---------------------------------------------------------------------------
__global__ __launch_bounds__(64, 1) void cif_fused_kernel(
    const float* __restrict__ hidden,
    const float* __restrict__ alphas,
    uint64_t* __restrict__ meta,     // [Bn*MSTRIDE]
    float* __restrict__ out) {
  const int lane = threadIdx.x;
  __shared__ __align__(16) float alds[Tn + 64];   // +pad: tail prefetch safe

  if (blockIdx.x < Bn) {
    // ---------------- producer: serial scan for row b ----------------
    __builtin_amdgcn_s_setprio(3);
    const int b = blockIdx.x;
    {  // stage row -> LDS, coalesced (one-time cost, outside the chain)
      const float4* __restrict__ arow =
          reinterpret_cast<const float4*>(alphas + (size_t)b * Tn);
      for (int i = lane; i < Tn / 4; i += 64)
        *reinterpret_cast<float4*>(&alds[4 * i]) = arow[i];
      for (int i = Tn / 4 + lane; i < (Tn + 64) / 4; i += 64)
        *reinterpret_cast<float4*>(&alds[4 * i]) =
            make_float4(0.f, 0.f, 0.f, 0.f);
    }
    __syncthreads();

    const float4* __restrict__ lds4 =
        reinterpret_cast<const float4*>(&alds[0]);
    float I  = 0.0f;
    int   fc = 0;

    float4 q0 = lds4[0], q1 = lds4[1], q2 = lds4[2], q3 = lds4[3],
           q4 = lds4[4];
    int rd = 5;

    auto step4 = [&](const float4& q) {
#pragma unroll
      for (int j = 0; j < 4; ++j) {
        const float a = (j == 0) ? q.x : (j == 1) ? q.y : (j == 2) ? q.z : q.w;
        const float integ = I + a;            // reference op order
        const bool  fire  = integ > kThresh;
        I  = fire ? (integ - 1.0f) : integ;
        fc += fire ? 1 : 0;
      }
    };

    for (int c = 0; c < 100; ++c) {           // 20 steps per iteration
      if (lane == 0 && (c & 1) == 0) {        // state at t = 20c -> chunk c/2
        const uint64_t v = ((uint64_t)__float_as_uint(I) << 32) |
                           (uint64_t)(PUBF | (unsigned)fc);
        __hip_atomic_store(&meta[(size_t)b * MSTRIDE + (c >> 1)], v,
                           __ATOMIC_RELAXED, __HIP_MEMORY_SCOPE_AGENT);
      }
      step4(q0); q0 = lds4[rd + 0];           // reload right after consume
      step4(q1); q1 = lds4[rd + 1];
      step4(q2); q2 = lds4[rd + 2];
      step4(q3); q3 = lds4[rd + 3];
      step4(q4); q4 = lds4[rd + 4];
      rd += 5;
    }
    return;
  }

  // ---------------- consumer: (chunk tc, row b, half) ----------------
  const int idx  = blockIdx.x - Bn;
  const int b    = idx & (Bn - 1);
  const int q    = idx >> 5;                // 0..NTCH*CSPLIT-1, low q first
  const int tc   = q >> 1;                  // low blockIdx -> low tc
  const int half = q & 1;
  const int t_start = tc * TCHUNK;
  const int col  = half * (Hn / CSPLIT) + lane * 4;   // float4 per lane

  auto wait_meta = [&](int c) -> uint64_t {
    const uint64_t* p = &meta[(size_t)b * MSTRIDE + c];
    uint64_t v;
    for (;;) {
      v = __hip_atomic_load(p, __ATOMIC_RELAXED, __HIP_MEMORY_SCOPE_AGENT);
      if ((unsigned)v & PUBF) break;
      __builtin_amdgcn_s_sleep(16);
    }
    return v;
  };

  const float* __restrict__ arow = alphas + (size_t)b * Tn;

  // Chunk-start state (bit-exact from producer).
  float I; int s;
  if (tc == 0) { I = 0.0f; s = 0; }
  else {
    const uint64_t v = wait_meta(tc);
    I = __uint_as_float((unsigned)(v >> 32));
    s = (int)((unsigned)v & 0xFFFFu);
  }

  // Walk back: find t_prev (last fire before t_start) and its remainder.
  int   t_prev   = -1;
  float rem_prev = 0.0f;
  for (int k = 1; tc - k >= 0 && t_prev < 0; ++k) {
    const int ck = tc - k;
    float Ik;
    if (ck == 0) Ik = 0.0f;
    else {
      const uint64_t v = wait_meta(ck);
      Ik = __uint_as_float((unsigned)(v >> 32));
    }
    const float* __restrict__ ap = arow + ck * TCHUNK;
    int lt = -1; float lrem = 0.0f;
#pragma unroll
    for (int j = 0; j < TCHUNK; ++j) {
      const float a     = ap[j];               // uniform scalar load
      const float integ = Ik + a;              // reference op order
      const bool  fire  = integ > kThresh;
      if (fire) { lt = ck * TCHUNK + j; lrem = a - (1.0f - Ik); }
      Ik = fire ? (integ - 1.0f) : integ;
    }
    if (lt >= 0) { t_prev = lt; rem_prev = lrem; }
  }

  const float* __restrict__ hb = hidden + (size_t)b * Tn * Hn + col;
  float4 acc = make_float4(0.f, 0.f, 0.f, 0.f);

  auto loadh = [&](int t) -> float4 {
    return *reinterpret_cast<const float4*>(hb + (size_t)t * Hn);
  };

  if (t_prev >= 0) {            // opening: frame = rem * h[t_prev]
    const float4 h = loadh(t_prev);
    acc.x = rem_prev * h.x; acc.y = rem_prev * h.y;
    acc.z = rem_prev * h.z; acc.w = rem_prev * h.w;
  }
  for (int t = t_prev + 1; t < t_start; ++t) {   // straddler interior rows
    const float a  = arow[t];
    const float4 h = loadh(t);
    acc.x += a * h.x; acc.y += a * h.y;
    acc.z += a * h.z; acc.w += a * h.w;
  }

  // Replay chunk tc with depth-2 h prefetch; close/store owned segments.
  float4 hc = loadh(t_start);
  for (int j = 0; j < TCHUNK; ++j) {
    const int t  = t_start + j;
    const int tn = (j + 1 < TCHUNK) ? t + 1 : t;   // clamp in-chunk
    const float4 hn = loadh(tn);             // issue BEFORE consuming hc
    const float a     = arow[t];             // uniform scalar load
    const float integ = I + a;               // reference op order
    const bool  fire  = integ > kThresh;     // wave-uniform
    if (fire) {
      const float cw = 1.0f - I;             // dist_completion
      acc.x += cw * hc.x; acc.y += cw * hc.y;
      acc.z += cw * hc.z; acc.w += cw * hc.w;
      if (s < Ln) {
        float* op = out + ((size_t)b * Ln + s) * Hn + col;
        *reinterpret_cast<float4*>(op) = acc;
      }
      const float rem = a - cw;              // remainds -> opens next segment
      acc.x = rem * hc.x; acc.y = rem * hc.y;
      acc.z = rem * hc.z; acc.w = rem * hc.w;
      s += 1;
      I  = integ - 1.0f;
    } else {
      acc.x += a * hc.x; acc.y += a * hc.y;
      acc.z += a * hc.z; acc.w += a * hc.w;
      I = integ;
    }
    hc = hn;
  }
  // Open tail is owned by consumer (tc+1); nothing more to store...
  if (tc == NTCH - 1) {                      // ...except zero-fill at the end
    const float4 z = make_float4(0.f, 0.f, 0.f, 0.f);
    for (int s2 = s; s2 < Ln; ++s2) {
      float* op = out + ((size_t)b * Ln + s2) * Hn + col;
      *reinterpret_cast<float4*>(op) = z;
    }
  }
}

extern "C" void kernel_launch(void* const* d_in, const int* in_sizes, int n_in,
                              void* d_out, int out_size, void* d_ws, size_t ws_size,
                              hipStream_t stream) {
  const float* hidden = (const float*)d_in[0];
  const float* alphas = (const float*)d_in[1];
  float* out = (float*)d_out;

  // ws layout: meta[Bn*MSTRIDE] u64 (16 KB, memset each call -- poison 0xAA
  // would read as published since bit30 of 0xAAAAAAAA is set).
  uint64_t* meta = (uint64_t*)d_ws;
  hipMemsetAsync(meta, 0, (size_t)Bn * MSTRIDE * sizeof(uint64_t), stream);

  const int nblocks = Bn + NTCH * Bn * CSPLIT;  // 32 producers + 3200 consumers
  cif_fused_kernel<<<nblocks, 64, 0, stream>>>(hidden, alphas, meta, out);
}

// Round 30
// 53.837 us; speedup vs baseline: 1.6483x; 1.0541x over previous
//
#include <hip/hip_runtime.h>
#include <stdint.h>

static constexpr int   Bn      = 32;
static constexpr int   Tn      = 2000;
static constexpr int   Hn      = 512;
static constexpr int   Ln      = 256;     // max_label_len
static constexpr float kThresh = 0.95f;
static constexpr int   TCHUNK  = 20;      // meta granularity (consumer chunk)
static constexpr int   NTCH    = Tn / TCHUNK;   // 100
static constexpr int   MSTRIDE = 128;           // meta entries per row (padded)
static constexpr unsigned PUBF = 0x40000000u;   // published flag (low word)

// ---------------------------------------------------------------------------
// Fused producer-consumer CIF. R30 = R23's resource equilibrium (LDS 8704 ->
// VGPR 44, 3232 co-resident blocks) at HALF the pipeline granularity:
// TCHUNK 40->20 with CSPLIT 2->1 (same 3200 consumers; each owns a full
// H-row slice, 8 floats/lane = 2 independent float4 loads per row -> 2x
// outstanding bytes per step for free). Producer publishes meta every 20
// steps (every rotation iteration). Mechanism: total = producer-finish +
// LAST consumer's post-meta work; halving the chunk halves that tail
// (~5-10 us -> ~3-5 us) and lets every consumer start ~20 steps earlier.
//
// Producer (blocks 0..31): LDS-staged alpha row, serial chain via depth-5
// rotation of named float4 (ds_read-fed, no vmem/arrays in the chain),
// meta = ONE relaxed 8-B atomic per 20 steps (meta IS the flag, no fence).
// Consumers (one per (chunk tc, row b)): spin with s_sleep on meta[tc],
// bit-exact replay of chunk tc, exclusive ownership of segments CLOSING in
// the chunk (walk-back re-derives the straddler opening), ascending-t
// accumulation = reference op order -> absmax 0.0; tc=NTCH-1 zero-fills
// [fc,256). No atomics, no pre-zero pass.
// ---------------------------------------------------------------------------
__global__ __launch_bounds__(64, 1) void cif_fused_kernel(
    const float* __restrict__ hidden,
    const float* __restrict__ alphas,
    uint64_t* __restrict__ meta,     // [Bn*MSTRIDE]
    float* __restrict__ out) {
  const int lane = threadIdx.x;
  __shared__ __align__(16) float alds[Tn + 64];   // +pad: tail prefetch safe

  if (blockIdx.x < Bn) {
    // ---------------- producer: serial scan for row b ----------------
    __builtin_amdgcn_s_setprio(3);
    const int b = blockIdx.x;
    {  // stage row -> LDS, coalesced (one-time cost, outside the chain)
      const float4* __restrict__ arow =
          reinterpret_cast<const float4*>(alphas + (size_t)b * Tn);
      for (int i = lane; i < Tn / 4; i += 64)
        *reinterpret_cast<float4*>(&alds[4 * i]) = arow[i];
      for (int i = Tn / 4 + lane; i < (Tn + 64) / 4; i += 64)
        *reinterpret_cast<float4*>(&alds[4 * i]) =
            make_float4(0.f, 0.f, 0.f, 0.f);
    }
    __syncthreads();

    const float4* __restrict__ lds4 =
        reinterpret_cast<const float4*>(&alds[0]);
    float I  = 0.0f;
    int   fc = 0;

    float4 q0 = lds4[0], q1 = lds4[1], q2 = lds4[2], q3 = lds4[3],
           q4 = lds4[4];
    int rd = 5;

    auto step4 = [&](const float4& q) {
#pragma unroll
      for (int j = 0; j < 4; ++j) {
        const float a = (j == 0) ? q.x : (j == 1) ? q.y : (j == 2) ? q.z : q.w;
        const float integ = I + a;            // reference op order
        const bool  fire  = integ > kThresh;
        I  = fire ? (integ - 1.0f) : integ;
        fc += fire ? 1 : 0;
      }
    };

    for (int c = 0; c < 100; ++c) {           // 20 steps per iteration
      if (lane == 0) {                        // state at t = 20c -> chunk c
        const uint64_t v = ((uint64_t)__float_as_uint(I) << 32) |
                           (uint64_t)(PUBF | (unsigned)fc);
        __hip_atomic_store(&meta[(size_t)b * MSTRIDE + c], v,
                           __ATOMIC_RELAXED, __HIP_MEMORY_SCOPE_AGENT);
      }
      step4(q0); q0 = lds4[rd + 0];           // reload right after consume
      step4(q1); q1 = lds4[rd + 1];
      step4(q2); q2 = lds4[rd + 2];
      step4(q3); q3 = lds4[rd + 3];
      step4(q4); q4 = lds4[rd + 4];
      rd += 5;
    }
    return;
  }

  // ---------------- consumer: (chunk tc, row b) ----------------
  const int idx = blockIdx.x - Bn;
  const int b   = idx & (Bn - 1);
  const int tc  = idx >> 5;                 // low blockIdx -> low tc
  const int t_start = tc * TCHUNK;
  const int col = lane * 8;                 // 8 floats/thread over H=512

  auto wait_meta = [&](int c) -> uint64_t {
    const uint64_t* p = &meta[(size_t)b * MSTRIDE + c];
    uint64_t v;
    for (;;) {
      v = __hip_atomic_load(p, __ATOMIC_RELAXED, __HIP_MEMORY_SCOPE_AGENT);
      if ((unsigned)v & PUBF) break;
      __builtin_amdgcn_s_sleep(16);
    }
    return v;
  };

  const float* __restrict__ arow = alphas + (size_t)b * Tn;

  // Chunk-start state (bit-exact from producer).
  float I; int s;
  if (tc == 0) { I = 0.0f; s = 0; }
  else {
    const uint64_t v = wait_meta(tc);
    I = __uint_as_float((unsigned)(v >> 32));
    s = (int)((unsigned)v & 0xFFFFu);
  }

  // Walk back: find t_prev (last fire before t_start) and its remainder.
  int   t_prev   = -1;
  float rem_prev = 0.0f;
  for (int k = 1; tc - k >= 0 && t_prev < 0; ++k) {
    const int ck = tc - k;
    float Ik;
    if (ck == 0) Ik = 0.0f;
    else {
      const uint64_t v = wait_meta(ck);
      Ik = __uint_as_float((unsigned)(v >> 32));
    }
    const float* __restrict__ ap = arow + ck * TCHUNK;
    int lt = -1; float lrem = 0.0f;
#pragma unroll
    for (int j = 0; j < TCHUNK; ++j) {
      const float a     = ap[j];               // uniform scalar load
      const float integ = Ik + a;              // reference op order
      const bool  fire  = integ > kThresh;
      if (fire) { lt = ck * TCHUNK + j; lrem = a - (1.0f - Ik); }
      Ik = fire ? (integ - 1.0f) : integ;
    }
    if (lt >= 0) { t_prev = lt; rem_prev = lrem; }
  }

  const float* __restrict__ hb = hidden + (size_t)b * Tn * Hn + col;
  float4 acc0 = make_float4(0.f, 0.f, 0.f, 0.f);
  float4 acc1 = make_float4(0.f, 0.f, 0.f, 0.f);

  auto loadh0 = [&](int t) -> float4 {
    return *reinterpret_cast<const float4*>(hb + (size_t)t * Hn);
  };
  auto loadh1 = [&](int t) -> float4 {
    return *reinterpret_cast<const float4*>(hb + (size_t)t * Hn + 4);
  };

  if (t_prev >= 0) {            // opening: frame = rem * h[t_prev]
    const float4 h0 = loadh0(t_prev);
    const float4 h1 = loadh1(t_prev);
    acc0.x = rem_prev * h0.x; acc0.y = rem_prev * h0.y;
    acc0.z = rem_prev * h0.z; acc0.w = rem_prev * h0.w;
    acc1.x = rem_prev * h1.x; acc1.y = rem_prev * h1.y;
    acc1.z = rem_prev * h1.z; acc1.w = rem_prev * h1.w;
  }
  for (int t = t_prev + 1; t < t_start; ++t) {   // straddler interior rows
    const float a   = arow[t];
    const float4 h0 = loadh0(t);
    const float4 h1 = loadh1(t);
    acc0.x += a * h0.x; acc0.y += a * h0.y;
    acc0.z += a * h0.z; acc0.w += a * h0.w;
    acc1.x += a * h1.x; acc1.y += a * h1.y;
    acc1.z += a * h1.z; acc1.w += a * h1.w;
  }

  // Replay chunk tc with depth-2 row prefetch; close/store owned segments.
  float4 c0 = loadh0(t_start);
  float4 c1 = loadh1(t_start);
  for (int j = 0; j < TCHUNK; ++j) {
    const int t  = t_start + j;
    const int tn = (j + 1 < TCHUNK) ? t + 1 : t;   // clamp in-chunk
    const float4 n0 = loadh0(tn);            // issue BEFORE consuming c0/c1
    const float4 n1 = loadh1(tn);
    const float a     = arow[t];             // uniform scalar load
    const float integ = I + a;               // reference op order
    const bool  fire  = integ > kThresh;     // wave-uniform
    if (fire) {
      const float cw = 1.0f - I;             // dist_completion
      acc0.x += cw * c0.x; acc0.y += cw * c0.y;
      acc0.z += cw * c0.z; acc0.w += cw * c0.w;
      acc1.x += cw * c1.x; acc1.y += cw * c1.y;
      acc1.z += cw * c1.z; acc1.w += cw * c1.w;
      if (s < Ln) {
        float* op = out + ((size_t)b * Ln + s) * Hn + col;
        *reinterpret_cast<float4*>(op)     = acc0;
        *reinterpret_cast<float4*>(op + 4) = acc1;
      }
      const float rem = a - cw;              // remainds -> opens next segment
      acc0.x = rem * c0.x; acc0.y = rem * c0.y;
      acc0.z = rem * c0.z; acc0.w = rem * c0.w;
      acc1.x = rem * c1.x; acc1.y = rem * c1.y;
      acc1.z = rem * c1.z; acc1.w = rem * c1.w;
      s += 1;
      I  = integ - 1.0f;
    } else {
      acc0.x += a * c0.x; acc0.y += a * c0.y;
      acc0.z += a * c0.z; acc0.w += a * c0.w;
      acc1.x += a * c1.x; acc1.y += a * c1.y;
      acc1.z += a * c1.z; acc1.w += a * c1.w;
      I = integ;
    }
    c0 = n0; c1 = n1;
  }
  // Open tail is owned by consumer (tc+1); nothing more to store...
  if (tc == NTCH - 1) {                      // ...except zero-fill at the end
    const float4 z = make_float4(0.f, 0.f, 0.f, 0.f);
    for (int s2 = s; s2 < Ln; ++s2) {
      float* op = out + ((size_t)b * Ln + s2) * Hn + col;
      *reinterpret_cast<float4*>(op)     = z;
      *reinterpret_cast<float4*>(op + 4) = z;
    }
  }
}

extern "C" void kernel_launch(void* const* d_in, const int* in_sizes, int n_in,
                              void* d_out, int out_size, void* d_ws, size_t ws_size,
                              hipStream_t stream) {
  const float* hidden = (const float*)d_in[0];
  const float* alphas = (const float*)d_in[1];
  float* out = (float*)d_out;

  // ws layout: meta[Bn*MSTRIDE] u64 (32 KB, memset each call -- poison 0xAA
  // would read as published since bit30 of 0xAAAAAAAA is set).
  uint64_t* meta = (uint64_t*)d_ws;
  hipMemsetAsync(meta, 0, (size_t)Bn * MSTRIDE * sizeof(uint64_t), stream);

  const int nblocks = Bn + NTCH * Bn;   // 32 producers + 3200 consumers
  cif_fused_kernel<<<nblocks, 64, 0, stream>>>(hidden, alphas, meta, out);
}